// Round 6
// baseline (472.767 us; speedup 1.0000x reference)
//
#include <hip/hip_runtime.h>

#define K1 3072
#define N1 1024
#define NCOL 50
#define BK 32
#define NSTEP (K1 / BK)   // 96
#define SAS 40            // A staging row stride (bf16) = 80 B (pad: 2-way free)
#define SBS 32            // B staging row stride (bf16) = 64 B (linear, gload_lds)
#define SHS 136           // h / w2t row stride = 272 B

typedef float  f32x4  __attribute__((ext_vector_type(4)));
typedef short  short8 __attribute__((ext_vector_type(8)));

// global_load_lds: 16B per lane, dest = wave-uniform LDS base + lane*16
#define GLD16(g, l)                                                        \
  __builtin_amdgcn_global_load_lds(                                        \
      (const __attribute__((address_space(1))) void*)(g),                  \
      (__attribute__((address_space(3))) void*)(l), 16, 0, 0)

__device__ inline unsigned bfr(float f) {          // round-half-up bf16 bits in lo16
  return (__builtin_bit_cast(unsigned, f) + 0x8000u) >> 16;
}
__device__ inline short f2bf(float f) { return (short)bfr(f); }
__device__ inline short8 cvt8(float4 a, float4 b) {
  short8 r;
  r[0] = f2bf(a.x); r[1] = f2bf(a.y); r[2] = f2bf(a.z); r[3] = f2bf(a.w);
  r[4] = f2bf(b.x); r[5] = f2bf(b.y); r[6] = f2bf(b.z); r[7] = f2bf(b.w);
  return r;
}

// ---------------- prep kernels (path 1) ----------------
// W1T[n][k] = bf16(W1[k][n]) — 64x64 LDS-tiled transpose
__global__ __launch_bounds__(256) void w1t_kernel(const float* __restrict__ W1,
                                                  short* __restrict__ W1T) {
  __shared__ float tile[64 * 65];
  const int t = threadIdx.x, b = blockIdx.x;
  const int k0 = (b >> 4) * 64, n0 = (b & 15) * 64;
#pragma unroll
  for (int i = 0; i < 16; ++i) {
    const int e = t + i * 256, r = e >> 6, c = e & 63;
    tile[r * 65 + c] = W1[(size_t)(k0 + r) * N1 + n0 + c];
  }
  __syncthreads();
#pragma unroll
  for (int i = 0; i < 16; ++i) {
    const int e = t + i * 256, kx = e & 63, ny = e >> 6;
    W1T[(size_t)(n0 + ny) * K1 + k0 + kx] = f2bf(tile[kx * 65 + ny]);
  }
}

// W2T[c][k] = bf16(W2[k][c]) for c<50, else 0 (64 padded rows)
__global__ __launch_bounds__(256) void w2t_kernel(const float* __restrict__ W2,
                                                  short* __restrict__ W2T) {
  const int idx = blockIdx.x * 256 + threadIdx.x;
  for (int e = idx; e < 64 * N1; e += 16 * 256) {
    const int c = e >> 10, k = e & 1023;
    const float v = (c < NCOL) ? W2[(size_t)k * NCOL + c] : 0.f;
    W2T[(size_t)c * N1 + k] = f2bf(v);
  }
}

// ---------------- main kernel, path 1 (uses W1T/W2T in ws) ----------------
struct __align__(16) Smem1 {
  union {
    struct { short A[128 * SAS]; short B[128 * SBS]; } s;   // 18.4 KB staging
    struct { short h[64 * SHS]; short w2t[64 * SHS]; } e;   // 34.8 KB epilogue
  } u;
};

__global__ __launch_bounds__(256, 4)
void hoi_fused1(const float* __restrict__ X, const short* __restrict__ W1T,
                const float* __restrict__ B1, const short* __restrict__ W2T,
                const float* __restrict__ B2, float* __restrict__ OUT) {
  __shared__ Smem1 sm;
  const int tid  = threadIdx.x;
  const int lane = tid & 63, wid = tid >> 6;
  const int wr = wid >> 1, wc = wid & 1;
  const int l15 = lane & 15, g = lane >> 4;

  // XCD-grouped swizzle: 8 n-blocks of one m-panel consecutive on ONE XCD
  const int bid   = blockIdx.x;
  const int xcd   = bid & 7, o = bid >> 3;
  const int m_blk = xcd * 32 + (o >> 3);
  const int n_blk = o & 7;
  const int m0 = m_blk * 128, n0 = n_blk * 128;

  // A staging (R5-proven): row = tid>>1, 16 f32 at akc
  const int arow = tid >> 1;
  const int akc  = (tid & 1) << 4;
  const float* aptr = X + (size_t)(m0 + arow) * K1 + akc;

  // B staging via global_load_lds: wave wid owns chunks {2wid, 2wid+1} (16 n-rows each)
  // swizzle: LDS[row][slot] holds global k-slot (slot ^ (row&3))  [16B slots]
  const int brow_l = lane >> 2;                               // 0..15 row-in-chunk
  const int bslot  = ((lane & 3) ^ (brow_l & 3)) * 8;         // swizzled k-slot (shorts)
  const short* bsrc0 = W1T + (size_t)(n0 + 32 * wid + brow_l) * K1 + bslot;
  const short* bsrc1 = bsrc0 + (size_t)16 * K1;
  short* bdst0 = &sm.u.s.B[(2 * wid) * 512];
  short* bdst1 = bdst0 + 512;

  float b1v[4];
#pragma unroll
  for (int nt = 0; nt < 4; ++nt) b1v[nt] = B1[n0 + wc * 64 + nt * 16 + l15];

  f32x4 acc[4][4] = {};
  float4 ra[4];
#pragma unroll
  for (int q = 0; q < 4; ++q) ra[q] = *(const float4*)(aptr + 4 * q);

  for (int step = 0; step < NSTEP; ++step) {
    __syncthreads();                       // prev frag reads done; buffers reusable

    // B tile: 2 gload_lds per wave (DMA overlaps the A cvt below)
    GLD16(bsrc0 + step * BK, bdst0);
    GLD16(bsrc1 + step * BK, bdst1);

    // A tile: cvt + 2 b128 writes
    *(short8*)&sm.u.s.A[arow * SAS + akc + 0] = cvt8(ra[0], ra[1]);
    *(short8*)&sm.u.s.A[arow * SAS + akc + 8] = cvt8(ra[2], ra[3]);

    // A(t+1) prefetch
    if (step + 1 < NSTEP) {
      const int k0v = (step + 1) * BK;
#pragma unroll
      for (int q = 0; q < 4; ++q) ra[q] = *(const float4*)(aptr + k0v + 4 * q);
    }

    __syncthreads();                       // drains vmcnt+lgkm: tile visible

    short8 af[4];
#pragma unroll
    for (int mt = 0; mt < 4; ++mt)
      af[mt] = *(const short8*)&sm.u.s.A[(wr * 64 + mt * 16 + l15) * SAS + g * 8];
#pragma unroll
    for (int nt = 0; nt < 4; ++nt) {
      const int nrow = wc * 64 + nt * 16 + l15;
      const short8 bfv =
          *(const short8*)&sm.u.s.B[nrow * SBS + ((g ^ (nrow & 3)) * 8)];
#pragma unroll
      for (int mt = 0; mt < 4; ++mt)
        acc[mt][nt] = __builtin_amdgcn_mfma_f32_16x16x32_bf16(af[mt], bfv, acc[mt][nt], 0, 0, 0);
    }
  }

  // ---- epilogue: two 64-row phases ----
  for (int p = 0; p < 2; ++p) {
    __syncthreads();

    if (wr == p) {
#pragma unroll
      for (int mt = 0; mt < 4; ++mt)
#pragma unroll
        for (int nt = 0; nt < 4; ++nt) {
          const int c = wc * 64 + nt * 16 + l15;
#pragma unroll
          for (int j = 0; j < 4; ++j) {
            const int r = mt * 16 + g * 4 + j;
            sm.u.e.h[r * SHS + c] = f2bf(fmaxf(acc[mt][nt][j] + b1v[nt], 0.f));
          }
        }
    }
    if (p == 0) {   // stage w2t slice from precomputed W2T (vectorized)
      const int c = tid >> 2, q = tid & 3;
#pragma unroll
      for (int i = 0; i < 4; ++i) {
        const short8 v = *(const short8*)(W2T + (size_t)c * N1 + n0 + q * 32 + i * 8);
        *(short8*)&sm.u.e.w2t[c * SHS + q * 32 + i * 8] = v;
      }
    }
    __syncthreads();

    f32x4 acc2[4] = {};
#pragma unroll
    for (int ks = 0; ks < 4; ++ks) {
      const short8 a2f = *(const short8*)&sm.u.e.h[(wid * 16 + l15) * SHS + ks * 32 + g * 8];
#pragma unroll
      for (int nt2 = 0; nt2 < 4; ++nt2) {
        const short8 b2f = *(const short8*)&sm.u.e.w2t[(nt2 * 16 + l15) * SHS + ks * 32 + g * 8];
        acc2[nt2] = __builtin_amdgcn_mfma_f32_16x16x32_bf16(a2f, b2f, acc2[nt2], 0, 0, 0);
      }
    }

#pragma unroll
    for (int nt2 = 0; nt2 < 4; ++nt2) {
      const int c = nt2 * 16 + l15;
      if (c < NCOL) {
#pragma unroll
        for (int j = 0; j < 4; ++j) {
          const int r = m0 + p * 64 + wid * 16 + g * 4 + j;
          float v = acc2[nt2][j];
          if (n_blk == 0) v += B2[c];
          atomicAdd(&OUT[(size_t)r * NCOL + c], v);
        }
      }
    }
  }
}

// ---------------- path 0: R5 fallback (no ws requirement) ----------------
struct __align__(16) Smem0 {
  union {
    struct { short A[128 * SAS]; short BT[128 * SAS]; } s[2];
    struct { short h[64 * SHS]; short w2t[64 * SHS]; } e;
  } u;
};

__global__ __launch_bounds__(256, 3)
void hoi_fused0(const float* __restrict__ X, const float* __restrict__ W1,
                const float* __restrict__ B1, const float* __restrict__ W2,
                const float* __restrict__ B2, float* __restrict__ OUT) {
  __shared__ Smem0 sm;
  const int tid  = threadIdx.x;
  const int lane = tid & 63, wid = tid >> 6;
  const int wr = wid >> 1, wc = wid & 1;
  const int l15 = lane & 15, g = lane >> 4;
  const int bid   = blockIdx.x;
  const int xcd   = bid & 7, o = bid >> 3;
  const int m_blk = xcd * 32 + (o >> 3);
  const int n_blk = o & 7;
  const int m0 = m_blk * 128, n0 = n_blk * 128;

  const int arow = tid >> 1;
  const int akc  = (tid & 1) << 4;
  const float* aptr = X + (size_t)(m0 + arow) * K1 + akc;
  const int bk2 = tid >> 4, bcm = tid & 15;
  const float* bptr = W1 + (size_t)(2 * bk2) * N1 + n0 + bcm;

  float b1v[4];
#pragma unroll
  for (int nt = 0; nt < 4; ++nt) b1v[nt] = B1[n0 + wc * 64 + nt * 16 + l15];

  f32x4 acc[4][4] = {};
  float4 ra[4];
  float  rb0[8], rb1[8];
#pragma unroll
  for (int q = 0; q < 4; ++q) ra[q] = *(const float4*)(aptr + 4 * q);
#pragma unroll
  for (int i = 0; i < 8; ++i) { rb0[i] = bptr[16 * i]; rb1[i] = bptr[N1 + 16 * i]; }

  for (int step = 0; step < NSTEP; ++step) {
    const int cb = step & 1;
    const short8 av0 = cvt8(ra[0], ra[1]);
    const short8 av1 = cvt8(ra[2], ra[3]);
    unsigned bpk[8];
#pragma unroll
    for (int i = 0; i < 8; ++i)
      bpk[i] = bfr(rb0[i]) |
               ((__builtin_bit_cast(unsigned, rb1[i]) + 0x8000u) & 0xFFFF0000u);
    if (step + 1 < NSTEP) {
      const int k0v = (step + 1) * BK;
#pragma unroll
      for (int q = 0; q < 4; ++q) ra[q] = *(const float4*)(aptr + k0v + 4 * q);
      const float* bp = bptr + (size_t)k0v * N1;
#pragma unroll
      for (int i = 0; i < 8; ++i) { rb0[i] = bp[16 * i]; rb1[i] = bp[N1 + 16 * i]; }
    }
    *(short8*)&sm.u.s[cb].A[arow * SAS + akc + 0] = av0;
    *(short8*)&sm.u.s[cb].A[arow * SAS + akc + 8] = av1;
#pragma unroll
    for (int i = 0; i < 8; ++i)
      *(unsigned*)&sm.u.s[cb].BT[(bcm + 16 * i) * SAS + 2 * bk2] = bpk[i];

    asm volatile("s_waitcnt lgkmcnt(0)" ::: "memory");
    __builtin_amdgcn_s_barrier();
    __builtin_amdgcn_sched_barrier(0);

    short8 af[4];
#pragma unroll
    for (int mt = 0; mt < 4; ++mt)
      af[mt] = *(const short8*)&sm.u.s[cb].A[(wr * 64 + mt * 16 + l15) * SAS + g * 8];
#pragma unroll
    for (int nt = 0; nt < 4; ++nt) {
      short8 bfv = *(const short8*)&sm.u.s[cb].BT[(wc * 64 + nt * 16 + l15) * SAS + g * 8];
#pragma unroll
      for (int mt = 0; mt < 4; ++mt)
        acc[mt][nt] = __builtin_amdgcn_mfma_f32_16x16x32_bf16(af[mt], bfv, acc[mt][nt], 0, 0, 0);
    }
  }

  for (int p = 0; p < 2; ++p) {
    __syncthreads();
    if (wr == p) {
#pragma unroll
      for (int mt = 0; mt < 4; ++mt)
#pragma unroll
        for (int nt = 0; nt < 4; ++nt) {
          const int c = wc * 64 + nt * 16 + l15;
#pragma unroll
          for (int j = 0; j < 4; ++j) {
            const int r = mt * 16 + g * 4 + j;
            sm.u.e.h[r * SHS + c] = f2bf(fmaxf(acc[mt][nt][j] + b1v[nt], 0.f));
          }
        }
    }
    if (p == 0) {
      const int kk = tid >> 1, ch = (tid & 1) * 32;
#pragma unroll
      for (int i = 0; i < 32; ++i) {
        const int c = ch + i;
        const float v = (c < NCOL) ? W2[(size_t)(n0 + kk) * NCOL + c] : 0.f;
        sm.u.e.w2t[c * SHS + kk] = f2bf(v);
      }
    }
    __syncthreads();

    f32x4 acc2[4] = {};
#pragma unroll
    for (int ks = 0; ks < 4; ++ks) {
      const short8 a2f = *(const short8*)&sm.u.e.h[(wid * 16 + l15) * SHS + ks * 32 + g * 8];
#pragma unroll
      for (int nt2 = 0; nt2 < 4; ++nt2) {
        const short8 b2f = *(const short8*)&sm.u.e.w2t[(nt2 * 16 + l15) * SHS + ks * 32 + g * 8];
        acc2[nt2] = __builtin_amdgcn_mfma_f32_16x16x32_bf16(a2f, b2f, acc2[nt2], 0, 0, 0);
      }
    }
#pragma unroll
    for (int nt2 = 0; nt2 < 4; ++nt2) {
      const int c = nt2 * 16 + l15;
      if (c < NCOL) {
#pragma unroll
        for (int j = 0; j < 4; ++j) {
          const int r = m0 + p * 64 + wid * 16 + g * 4 + j;
          float v = acc2[nt2][j];
          if (n_blk == 0) v += B2[c];
          atomicAdd(&OUT[(size_t)r * NCOL + c], v);
        }
      }
    }
  }
}

extern "C" void kernel_launch(void* const* d_in, const int* in_sizes, int n_in,
                              void* d_out, int out_size, void* d_ws, size_t ws_size,
                              hipStream_t stream) {
  const float* X  = (const float*)d_in[0];
  const float* W1 = (const float*)d_in[1];
  const float* B1 = (const float*)d_in[2];
  const float* W2 = (const float*)d_in[3];
  const float* B2 = (const float*)d_in[4];
  float* OUT = (float*)d_out;

  const size_t W1T_BYTES = (size_t)N1 * K1 * 2;   // 6,291,456
  const size_t W2T_BYTES = (size_t)64 * N1 * 2;   // 131,072

  hipMemsetAsync(d_out, 0, (size_t)out_size * sizeof(float), stream);

  if (ws_size >= W1T_BYTES + W2T_BYTES) {
    short* W1T = (short*)d_ws;
    short* W2T = (short*)((char*)d_ws + W1T_BYTES);
    hipLaunchKernelGGL(w1t_kernel, dim3(768), dim3(256), 0, stream, W1, W1T);
    hipLaunchKernelGGL(w2t_kernel, dim3(16), dim3(256), 0, stream, W2, W2T);
    hipLaunchKernelGGL(hoi_fused1, dim3(2048), dim3(256), 0, stream, X, W1T, B1, W2T, B2, OUT);
  } else {
    hipLaunchKernelGGL(hoi_fused0, dim3(2048), dim3(256), 0, stream, X, W1, B1, W2, B2, OUT);
  }
}

// Round 7
// 433.754 us; speedup vs baseline: 1.0899x; 1.0899x over previous
//
#include <hip/hip_runtime.h>

#define K1 3072
#define N1 1024
#define NCOL 50
#define BK 32
#define NSTEP (K1 / BK)   // 96
#define SAS 40            // A staging row stride (bf16) = 80 B (pad: 2-way free)
#define SBS 32            // B staging row stride (bf16) = 64 B (linear, gload_lds)
#define SBUF (128 * SBS)  // one B buffer (shorts)
#define SHS 136           // h / w2t row stride = 272 B

typedef float  f32x4  __attribute__((ext_vector_type(4)));
typedef short  short8 __attribute__((ext_vector_type(8)));

// global_load_lds: 16B per lane, dest = wave-uniform LDS base + lane*16
#define GLD16(g, l)                                                        \
  __builtin_amdgcn_global_load_lds(                                        \
      (const __attribute__((address_space(1))) void*)(g),                  \
      (__attribute__((address_space(3))) void*)(l), 16, 0, 0)

__device__ inline unsigned bfr(float f) {          // round-half-up bf16 bits in lo16
  return (__builtin_bit_cast(unsigned, f) + 0x8000u) >> 16;
}
__device__ inline short f2bf(float f) { return (short)bfr(f); }
__device__ inline short8 cvt8(float4 a, float4 b) {
  short8 r;
  r[0] = f2bf(a.x); r[1] = f2bf(a.y); r[2] = f2bf(a.z); r[3] = f2bf(a.w);
  r[4] = f2bf(b.x); r[5] = f2bf(b.y); r[6] = f2bf(b.z); r[7] = f2bf(b.w);
  return r;
}

// ---------------- prep kernels (path 1) ----------------
__global__ __launch_bounds__(256) void w1t_kernel(const float* __restrict__ W1,
                                                  short* __restrict__ W1T) {
  __shared__ float tile[64 * 65];
  const int t = threadIdx.x, b = blockIdx.x;
  const int k0 = (b >> 4) * 64, n0 = (b & 15) * 64;
#pragma unroll
  for (int i = 0; i < 16; ++i) {
    const int e = t + i * 256, r = e >> 6, c = e & 63;
    tile[r * 65 + c] = W1[(size_t)(k0 + r) * N1 + n0 + c];
  }
  __syncthreads();
#pragma unroll
  for (int i = 0; i < 16; ++i) {
    const int e = t + i * 256, kx = e & 63, ny = e >> 6;
    W1T[(size_t)(n0 + ny) * K1 + k0 + kx] = f2bf(tile[kx * 65 + ny]);
  }
}

__global__ __launch_bounds__(256) void w2t_kernel(const float* __restrict__ W2,
                                                  short* __restrict__ W2T) {
  const int idx = blockIdx.x * 256 + threadIdx.x;
  for (int e = idx; e < 64 * N1; e += 16 * 256) {
    const int c = e >> 10, k = e & 1023;
    const float v = (c < NCOL) ? W2[(size_t)k * NCOL + c] : 0.f;
    W2T[(size_t)c * N1 + k] = f2bf(v);
  }
}

// ---------------- main kernel, path 1 ----------------
struct __align__(16) Smem1 {
  union {
    struct { short A[2][128 * SAS]; short B[2][128 * SBS]; } s;  // 36.5 KB dbuf
    struct { short h[64 * SHS]; short w2t[64 * SHS]; } e;        // 34.8 KB epilogue
  } u;
};

__global__ __launch_bounds__(256, 4)
void hoi_fused1(const float* __restrict__ X, const short* __restrict__ W1T,
                const float* __restrict__ B1, const short* __restrict__ W2T,
                const float* __restrict__ B2, float* __restrict__ OUT) {
  __shared__ Smem1 sm;
  const int tid  = threadIdx.x;
  const int lane = tid & 63, wid = tid >> 6;
  const int wr = wid >> 1, wc = wid & 1;
  const int l15 = lane & 15, g = lane >> 4;

  // XCD-grouped swizzle: 8 n-blocks of one m-panel consecutive on ONE XCD
  const int bid   = blockIdx.x;
  const int xcd   = bid & 7, o = bid >> 3;
  const int m_blk = xcd * 32 + (o >> 3);
  const int n_blk = o & 7;
  const int m0 = m_blk * 128, n0 = n_blk * 128;

  // A staging: row = tid>>1, 16 f32 at akc
  const int arow = tid >> 1;
  const int akc  = (tid & 1) << 4;
  const float* aptr = X + (size_t)(m0 + arow) * K1 + akc;

  // B staging via gload_lds: wave owns chunks {2wid, 2wid+1} (16 n-rows each)
  // swizzle: LDS[row][slot] = global k-slot (slot ^ (row&3))  [16B slots]
  const int brow_l = lane >> 2;
  const int bslot  = ((lane & 3) ^ (brow_l & 3)) * 8;
  const short* bsrc0 = W1T + (size_t)(n0 + 32 * wid + brow_l) * K1 + bslot;
  const short* bsrc1 = bsrc0 + (size_t)16 * K1;
  short* const bbase = &sm.u.s.B[0][2 * wid * 512];   // + buf*SBUF, +512 for chunk 1

  float b1v[4];
#pragma unroll
  for (int nt = 0; nt < 4; ++nt) b1v[nt] = B1[n0 + wc * 64 + nt * 16 + l15];

  f32x4 acc[4][4] = {};
  float4 ra[4];

  // ---- prologue: B(0) DMA, A(0) reg loads ----
  GLD16(bsrc0, bbase);
  GLD16(bsrc1, bbase + 512);
#pragma unroll
  for (int q = 0; q < 4; ++q) ra[q] = *(const float4*)(aptr + 4 * q);

  for (int step = 0; step < NSTEP; ++step) {
    const int cb = step & 1;

    // 1. cvt A(t)  (compiler waits vmcnt only for ra — issued a full step ago)
    const short8 av0 = cvt8(ra[0], ra[1]);
    const short8 av1 = cvt8(ra[2], ra[3]);
    // 2. ds_write A(t) -> LDS.A[cb]
    *(short8*)&sm.u.s.A[cb][arow * SAS + akc + 0] = av0;
    *(short8*)&sm.u.s.A[cb][arow * SAS + akc + 8] = av1;
    // 3. issue A(t+1) reg loads (clamped -> uniform vmcnt count incl. last step)
    {
      const int k0v = (step + 1 < NSTEP ? step + 1 : 0) * BK;
#pragma unroll
      for (int q = 0; q < 4; ++q) ra[q] = *(const float4*)(aptr + k0v + 4 * q);
    }
    __builtin_amdgcn_sched_barrier(0);
    // 4. retire B(t) DMA only; the 4 fresh A-loads stay in flight
    asm volatile("s_waitcnt vmcnt(4)" ::: "memory");
    // 5. A ds_writes visible
    asm volatile("s_waitcnt lgkmcnt(0)" ::: "memory");
    // 6. barrier: tile t (A writes + B DMA) visible to all waves
    __builtin_amdgcn_s_barrier();
    __builtin_amdgcn_sched_barrier(0);
    // 7. issue B(t+1) DMA into the other buffer (readers of it pre-date this barrier)
    if (step + 1 < NSTEP) {
      short* bd = bbase + (cb ^ 1) * SBUF;
      GLD16(bsrc0 + (step + 1) * BK, bd);
      GLD16(bsrc1 + (step + 1) * BK, bd + 512);
    }
    __builtin_amdgcn_sched_barrier(0);

    // 8. frag reads + MFMA on tile t
    short8 af[4];
#pragma unroll
    for (int mt = 0; mt < 4; ++mt)
      af[mt] = *(const short8*)&sm.u.s.A[cb][(wr * 64 + mt * 16 + l15) * SAS + g * 8];
#pragma unroll
    for (int nt = 0; nt < 4; ++nt) {
      const int nrow = wc * 64 + nt * 16 + l15;
      const short8 bfv =
          *(const short8*)&sm.u.s.B[cb][nrow * SBS + ((g ^ (nrow & 3)) * 8)];
#pragma unroll
      for (int mt = 0; mt < 4; ++mt)
        acc[mt][nt] = __builtin_amdgcn_mfma_f32_16x16x32_bf16(af[mt], bfv, acc[mt][nt], 0, 0, 0);
    }
  }

  // ---- epilogue: two 64-row phases (unchanged, R6-proven) ----
  for (int p = 0; p < 2; ++p) {
    __syncthreads();   // also drains the leftover clamped A loads (p=0)

    if (wr == p) {
#pragma unroll
      for (int mt = 0; mt < 4; ++mt)
#pragma unroll
        for (int nt = 0; nt < 4; ++nt) {
          const int c = wc * 64 + nt * 16 + l15;
#pragma unroll
          for (int j = 0; j < 4; ++j) {
            const int r = mt * 16 + g * 4 + j;
            sm.u.e.h[r * SHS + c] = f2bf(fmaxf(acc[mt][nt][j] + b1v[nt], 0.f));
          }
        }
    }
    if (p == 0) {
      const int c = tid >> 2, q = tid & 3;
#pragma unroll
      for (int i = 0; i < 4; ++i) {
        const short8 v = *(const short8*)(W2T + (size_t)c * N1 + n0 + q * 32 + i * 8);
        *(short8*)&sm.u.e.w2t[c * SHS + q * 32 + i * 8] = v;
      }
    }
    __syncthreads();

    f32x4 acc2[4] = {};
#pragma unroll
    for (int ks = 0; ks < 4; ++ks) {
      const short8 a2f = *(const short8*)&sm.u.e.h[(wid * 16 + l15) * SHS + ks * 32 + g * 8];
#pragma unroll
      for (int nt2 = 0; nt2 < 4; ++nt2) {
        const short8 b2f = *(const short8*)&sm.u.e.w2t[(nt2 * 16 + l15) * SHS + ks * 32 + g * 8];
        acc2[nt2] = __builtin_amdgcn_mfma_f32_16x16x32_bf16(a2f, b2f, acc2[nt2], 0, 0, 0);
      }
    }

#pragma unroll
    for (int nt2 = 0; nt2 < 4; ++nt2) {
      const int c = nt2 * 16 + l15;
      if (c < NCOL) {
#pragma unroll
        for (int j = 0; j < 4; ++j) {
          const int r = m0 + p * 64 + wid * 16 + g * 4 + j;
          float v = acc2[nt2][j];
          if (n_blk == 0) v += B2[c];
          atomicAdd(&OUT[(size_t)r * NCOL + c], v);
        }
      }
    }
  }
}

// ---------------- path 0: R5 fallback (no ws requirement) ----------------
struct __align__(16) Smem0 {
  union {
    struct { short A[128 * SAS]; short BT[128 * SAS]; } s[2];
    struct { short h[64 * SHS]; short w2t[64 * SHS]; } e;
  } u;
};

__global__ __launch_bounds__(256, 3)
void hoi_fused0(const float* __restrict__ X, const float* __restrict__ W1,
                const float* __restrict__ B1, const float* __restrict__ W2,
                const float* __restrict__ B2, float* __restrict__ OUT) {
  __shared__ Smem0 sm;
  const int tid  = threadIdx.x;
  const int lane = tid & 63, wid = tid >> 6;
  const int wr = wid >> 1, wc = wid & 1;
  const int l15 = lane & 15, g = lane >> 4;
  const int bid   = blockIdx.x;
  const int xcd   = bid & 7, o = bid >> 3;
  const int m_blk = xcd * 32 + (o >> 3);
  const int n_blk = o & 7;
  const int m0 = m_blk * 128, n0 = n_blk * 128;

  const int arow = tid >> 1;
  const int akc  = (tid & 1) << 4;
  const float* aptr = X + (size_t)(m0 + arow) * K1 + akc;
  const int bk2 = tid >> 4, bcm = tid & 15;
  const float* bptr = W1 + (size_t)(2 * bk2) * N1 + n0 + bcm;

  float b1v[4];
#pragma unroll
  for (int nt = 0; nt < 4; ++nt) b1v[nt] = B1[n0 + wc * 64 + nt * 16 + l15];

  f32x4 acc[4][4] = {};
  float4 ra[4];
  float  rb0[8], rb1[8];
#pragma unroll
  for (int q = 0; q < 4; ++q) ra[q] = *(const float4*)(aptr + 4 * q);
#pragma unroll
  for (int i = 0; i < 8; ++i) { rb0[i] = bptr[16 * i]; rb1[i] = bptr[N1 + 16 * i]; }

  for (int step = 0; step < NSTEP; ++step) {
    const int cb = step & 1;
    const short8 av0 = cvt8(ra[0], ra[1]);
    const short8 av1 = cvt8(ra[2], ra[3]);
    unsigned bpk[8];
#pragma unroll
    for (int i = 0; i < 8; ++i)
      bpk[i] = bfr(rb0[i]) |
               ((__builtin_bit_cast(unsigned, rb1[i]) + 0x8000u) & 0xFFFF0000u);
    if (step + 1 < NSTEP) {
      const int k0v = (step + 1) * BK;
#pragma unroll
      for (int q = 0; q < 4; ++q) ra[q] = *(const float4*)(aptr + k0v + 4 * q);
      const float* bp = bptr + (size_t)k0v * N1;
#pragma unroll
      for (int i = 0; i < 8; ++i) { rb0[i] = bp[16 * i]; rb1[i] = bp[N1 + 16 * i]; }
    }
    *(short8*)&sm.u.s[cb].A[arow * SAS + akc + 0] = av0;
    *(short8*)&sm.u.s[cb].A[arow * SAS + akc + 8] = av1;
#pragma unroll
    for (int i = 0; i < 8; ++i)
      *(unsigned*)&sm.u.s[cb].BT[(bcm + 16 * i) * SAS + 2 * bk2] = bpk[i];

    asm volatile("s_waitcnt lgkmcnt(0)" ::: "memory");
    __builtin_amdgcn_s_barrier();
    __builtin_amdgcn_sched_barrier(0);

    short8 af[4];
#pragma unroll
    for (int mt = 0; mt < 4; ++mt)
      af[mt] = *(const short8*)&sm.u.s[cb].A[(wr * 64 + mt * 16 + l15) * SAS + g * 8];
#pragma unroll
    for (int nt = 0; nt < 4; ++nt) {
      short8 bfv = *(const short8*)&sm.u.s[cb].BT[(wc * 64 + nt * 16 + l15) * SAS + g * 8];
#pragma unroll
      for (int mt = 0; mt < 4; ++mt)
        acc[mt][nt] = __builtin_amdgcn_mfma_f32_16x16x32_bf16(af[mt], bfv, acc[mt][nt], 0, 0, 0);
    }
  }

  for (int p = 0; p < 2; ++p) {
    __syncthreads();
    if (wr == p) {
#pragma unroll
      for (int mt = 0; mt < 4; ++mt)
#pragma unroll
        for (int nt = 0; nt < 4; ++nt) {
          const int c = wc * 64 + nt * 16 + l15;
#pragma unroll
          for (int j = 0; j < 4; ++j) {
            const int r = mt * 16 + g * 4 + j;
            sm.u.e.h[r * SHS + c] = f2bf(fmaxf(acc[mt][nt][j] + b1v[nt], 0.f));
          }
        }
    }
    if (p == 0) {
      const int kk = tid >> 1, ch = (tid & 1) * 32;
#pragma unroll
      for (int i = 0; i < 32; ++i) {
        const int c = ch + i;
        const float v = (c < NCOL) ? W2[(size_t)(n0 + kk) * NCOL + c] : 0.f;
        sm.u.e.w2t[c * SHS + kk] = f2bf(v);
      }
    }
    __syncthreads();

    f32x4 acc2[4] = {};
#pragma unroll
    for (int ks = 0; ks < 4; ++ks) {
      const short8 a2f = *(const short8*)&sm.u.e.h[(wid * 16 + l15) * SHS + ks * 32 + g * 8];
#pragma unroll
      for (int nt2 = 0; nt2 < 4; ++nt2) {
        const short8 b2f = *(const short8*)&sm.u.e.w2t[(nt2 * 16 + l15) * SHS + ks * 32 + g * 8];
        acc2[nt2] = __builtin_amdgcn_mfma_f32_16x16x32_bf16(a2f, b2f, acc2[nt2], 0, 0, 0);
      }
    }
#pragma unroll
    for (int nt2 = 0; nt2 < 4; ++nt2) {
      const int c = nt2 * 16 + l15;
      if (c < NCOL) {
#pragma unroll
        for (int j = 0; j < 4; ++j) {
          const int r = m0 + p * 64 + wid * 16 + g * 4 + j;
          float v = acc2[nt2][j];
          if (n_blk == 0) v += B2[c];
          atomicAdd(&OUT[(size_t)r * NCOL + c], v);
        }
      }
    }
  }
}

extern "C" void kernel_launch(void* const* d_in, const int* in_sizes, int n_in,
                              void* d_out, int out_size, void* d_ws, size_t ws_size,
                              hipStream_t stream) {
  const float* X  = (const float*)d_in[0];
  const float* W1 = (const float*)d_in[1];
  const float* B1 = (const float*)d_in[2];
  const float* W2 = (const float*)d_in[3];
  const float* B2 = (const float*)d_in[4];
  float* OUT = (float*)d_out;

  const size_t W1T_BYTES = (size_t)N1 * K1 * 2;
  const size_t W2T_BYTES = (size_t)64 * N1 * 2;

  hipMemsetAsync(d_out, 0, (size_t)out_size * sizeof(float), stream);

  if (ws_size >= W1T_BYTES + W2T_BYTES) {
    short* W1T = (short*)d_ws;
    short* W2T = (short*)((char*)d_ws + W1T_BYTES);
    hipLaunchKernelGGL(w1t_kernel, dim3(768), dim3(256), 0, stream, W1, W1T);
    hipLaunchKernelGGL(w2t_kernel, dim3(16), dim3(256), 0, stream, W2, W2T);
    hipLaunchKernelGGL(hoi_fused1, dim3(2048), dim3(256), 0, stream, X, W1T, B1, W2T, B2, OUT);
  } else {
    hipLaunchKernelGGL(hoi_fused0, dim3(2048), dim3(256), 0, stream, X, W1, B1, W2, B2, OUT);
  }
}